// Round 6
// baseline (2203.731 us; speedup 1.0000x reference)
//
#include <hip/hip_runtime.h>
#include <hip/hip_bf16.h>
#include <math.h>

// ---------------------------------------------------------------------------
// Residual VQ: N=32768 rows, D=768, Q=4 levels, V=4096 codewords.
//   Stage 1: fp16 MFMA GEMM shortlist (top-2 per 128-col block).
//   Stage 2: noisy top-4 of 64; if top-2 gap >= 1.0 take the winner directly
//            (fp16 noise sigma ~0.09 => Z~11 safe); else rescore top-4 with a
//            bit-exact emulation of numpy's fp32 BLAS path:
//            OpenBLAS sgemm (ZEN/Haswell): kc=384 K-blocks, serial FMA chain
//            ascending k per C element (one rounding/term), blocks combined
//            with one fp32 add; score = fl(2*dot) - norm (np pairwise-sum
//            norms, scalar 8-acc leaves under AVX512 dispatch).
//            Residual chain in plain f32 = bit-identical to the np mirror.
// ---------------------------------------------------------------------------

typedef _Float16 f16x8 __attribute__((ext_vector_type(8)));
typedef _Float16 f16x4 __attribute__((ext_vector_type(4)));
typedef float    f32x4 __attribute__((ext_vector_type(4)));

constexpr int N_ROWS = 32768;
constexpr int DIM    = 768;
constexpr int NQ     = 4;
constexpr int VCB    = 4096;
constexpr int BM = 128, BN = 128, BK = 32;
constexpr int NVB    = VCB / BN;   // 32 column blocks
constexpr int KSTEPS = DIM / BK;   // 24

#define GLD_LDS16(g, l) __builtin_amdgcn_global_load_lds(                     \
    (const __attribute__((address_space(1))) void*)(g),                       \
    (__attribute__((address_space(3))) void*)(l), 16, 0, 0)

// --- codebook prep: fp16 split + numpy-pairwise-f32 squared norms -----------
// np.sum(cb*cb,-1): pairwise 768->(384,384)->(192,192)->(96,96) leaves; leaf
// n=96 <= 8*vstep(16, AVX512) => scalar 8-accumulator path; combine = scalar
// adds per recursion level (butterfly xor 1,2,4 over the 8 leaf sums).
__global__ __launch_bounds__(256) void prep_cb(const float* __restrict__ cb,
                                               _Float16* __restrict__ cb_hi,
                                               float* __restrict__ cb_norm) {
  const int lane = threadIdx.x & 63;
  const int row  = blockIdx.x * 4 + (threadIdx.x >> 6);  // q*V + v
  const size_t base = (size_t)row * DIM;
#pragma unroll
  for (int i = 0; i < DIM / 64; ++i) {
    const int e = i * 64 + lane;
    cb_hi[base + e] = (_Float16)cb[base + e];
  }
  float B = 0.0f;
  if (lane < 8) {
    const float* p = cb + base + lane * 96;
    float r8[8];
#pragma unroll
    for (int a = 0; a < 8; ++a) r8[a] = __fmul_rn(p[a], p[a]);
#pragma unroll
    for (int k = 1; k < 12; ++k)
#pragma unroll
      for (int a = 0; a < 8; ++a)
        r8[a] = __fadd_rn(r8[a], __fmul_rn(p[k * 8 + a], p[k * 8 + a]));
    const float s01 = __fadd_rn(r8[0], r8[1]);
    const float s23 = __fadd_rn(r8[2], r8[3]);
    const float s45 = __fadd_rn(r8[4], r8[5]);
    const float s67 = __fadd_rn(r8[6], r8[7]);
    B = __fadd_rn(__fadd_rn(s01, s23), __fadd_rn(s45, s67));
  }
  B = __fadd_rn(B, __shfl_xor(B, 1));
  B = __fadd_rn(B, __shfl_xor(B, 2));
  B = __fadd_rn(B, __shfl_xor(B, 4));
  if (lane == 0) cb_norm[row] = B;
}

// --- x -> fp16 (level-0 GEMM A operand) -------------------------------------
__global__ __launch_bounds__(256) void split_x(const float* __restrict__ x,
                                               _Float16* __restrict__ r_hi) {
  const int stride = gridDim.x * blockDim.x;
  for (int i = blockIdx.x * blockDim.x + threadIdx.x; i < N_ROWS * DIM / 4;
       i += stride) {
    const float4 v = ((const float4*)x)[i];
    f16x4 h;
    h[0] = (_Float16)v.x; h[1] = (_Float16)v.y;
    h[2] = (_Float16)v.z; h[3] = (_Float16)v.w;
    ((f16x4*)r_hi)[i] = h;
  }
}

// --- stage 1: fp16 GEMM + per-(row, 128-col-block) top-2 --------------------
__global__ __launch_bounds__(256) void score_topk(
    const _Float16* __restrict__ A,   // [N_ROWS][DIM]
    const _Float16* __restrict__ B,   // [VCB][DIM]  (level slice)
    const float* __restrict__ bnorm,  // [VCB]       (level slice)
    float4* __restrict__ part) {      // [N_ROWS][NVB] (s0, v0, s1, v1)
  __shared__ _Float16 As[BM][BK];
  __shared__ _Float16 Bs[BN][BK];
  __shared__ float nrm[BN];
  __shared__ float sred[BM][2][2];
  __shared__ int   vred[BM][2][2];

  const int t  = threadIdx.x;
  const int bm = blockIdx.x >> 5;
  const int bv = blockIdx.x & 31;
  const int w = t >> 6, lane = t & 63;
  const int wm = w >> 1, wn = w & 1;
  const int fr = lane & 15, kg = lane >> 4;

  if (t < BN) nrm[t] = bnorm[bv * BN + t];

  f32x4 acc[4][4] = {};

  const int arow = t >> 2, acol = (t & 3) * 8;
  const _Float16* ga = A + (size_t)(bm * BM + arow) * DIM + acol;
  const _Float16* gb = B + (size_t)(bv * BN + arow) * DIM + acol;
  char* asBase = (char*)(&As[0][0]) + w * 1024;  // wave-uniform LDS dest
  char* bsBase = (char*)(&Bs[0][0]) + w * 1024;

  for (int s = 0; s < KSTEPS; ++s) {
    __syncthreads();                 // protect LDS vs previous ds_reads
    GLD_LDS16(ga,            asBase);
    GLD_LDS16(ga + 64 * DIM, asBase + 4096);
    GLD_LDS16(gb,            bsBase);
    GLD_LDS16(gb + 64 * DIM, bsBase + 4096);
    ga += BK; gb += BK;
    __syncthreads();                 // drains vmcnt(0): staging complete
    f16x8 af[4], bf[4];
#pragma unroll
    for (int i = 0; i < 4; ++i)
      af[i] = *(const f16x8*)(&As[wm * 64 + i * 16 + fr][kg * 8]);
#pragma unroll
    for (int j = 0; j < 4; ++j)
      bf[j] = *(const f16x8*)(&Bs[wn * 64 + j * 16 + fr][kg * 8]);
#pragma unroll
    for (int i = 0; i < 4; ++i)
#pragma unroll
      for (int j = 0; j < 4; ++j)
        acc[i][j] =
            __builtin_amdgcn_mfma_f32_16x16x32_f16(af[i], bf[j], acc[i][j], 0, 0, 0);
  }

  // epilogue: C/D layout col=lane&15, row=(lane>>4)*4+reg  [m89-verified]
#pragma unroll
  for (int i = 0; i < 4; ++i) {
#pragma unroll
    for (int r = 0; r < 4; ++r) {
      float s0 = -INFINITY, s1 = -INFINITY;
      int v0 = 0, v1 = 0;
#pragma unroll
      for (int j = 0; j < 4; ++j) {
        const int col = wn * 64 + j * 16 + fr;
        const float sc = 2.0f * acc[i][j][r] - nrm[col];
        const int vv = bv * BN + col;
        if (sc > s0)      { s1 = s0; v1 = v0; s0 = sc; v0 = vv; }
        else if (sc > s1) { s1 = sc; v1 = vv; }
      }
#pragma unroll
      for (int off = 1; off < 16; off <<= 1) {  // reduce over the 16 col-lanes
        const float os0 = __shfl_xor(s0, off); const int ov0 = __shfl_xor(v0, off);
        const float os1 = __shfl_xor(s1, off); const int ov1 = __shfl_xor(v1, off);
        if (os0 > s0) {
          const float ns1 = fmaxf(s0, os1);
          v1 = (s0 >= os1) ? v0 : ov1; s1 = ns1; s0 = os0; v0 = ov0;
        } else if (os0 > s1) { s1 = os0; v1 = ov0; }
      }
      if (fr == 0) {
        const int rl = wm * 64 + i * 16 + kg * 4 + r;
        sred[rl][wn][0] = s0; sred[rl][wn][1] = s1;
        vred[rl][wn][0] = v0; vred[rl][wn][1] = v1;
      }
    }
  }
  __syncthreads();
  if (t < BM) {
    float s0 = sred[t][0][0], s1 = sred[t][0][1];
    int   v0 = vred[t][0][0], v1 = vred[t][0][1];
    const float b0 = sred[t][1][0], b1 = sred[t][1][1];
    const int   u0 = vred[t][1][0], u1 = vred[t][1][1];
    if (b0 > s0) {
      const float ns1 = fmaxf(s0, b1);
      v1 = (s0 >= b1) ? v0 : u1; s1 = ns1; s0 = b0; v0 = u0;
    } else if (b0 > s1) { s1 = b0; v1 = u0; }
    float4 o;
    o.x = s0; o.y = __int_as_float(v0); o.z = s1; o.w = __int_as_float(v1);
    part[(size_t)(bm * BM + t) * NVB + bv] = o;
  }
}

// --- stage 2: gated argmax + residual update --------------------------------
// 32 threads per row. Noisy top-4 of 64 candidates; gap>=1.0 => winner direct;
// else lanes 0-3 emulate numpy/OpenBLAS fp32 sgemm per candidate:
//   p1 = serial FMA chain k=0..383; p2 = k=384..767; dot = fl(p1+p2);
//   score = fl( fl(2*dot) - norm ); argmax w/ lowest-v tie-break.
__global__ __launch_bounds__(256) void reduce_update(
    const float4* __restrict__ part,
    const float* __restrict__ cb,       // level slice [VCB][DIM] fp32
    const float* __restrict__ nrm_np,   // level slice norms (np-pairwise f32)
    const float* __restrict__ rsrc,     // x (q==0) or resid
    float* __restrict__ resid,
    float* __restrict__ quant,          // d_out[0 .. N*D)
    float* __restrict__ idx_out,        // d_out + N*D
    _Float16* __restrict__ r_hi,        // next-level GEMM A operand
    const int q) {
  const int t   = threadIdx.x;
  const int row = blockIdx.x * 8 + (t >> 5);
  const int j32 = t & 31;
  const size_t rb = (size_t)row * DIM;

  // Phase A: noisy top-4 of 64 candidates (32-lane butterfly)
  float cs[2]; int cv[2];
  {
    const float4 p = part[(size_t)row * NVB + j32];
    cs[0] = p.x; cv[0] = __float_as_int(p.y);
    cs[1] = p.z; cv[1] = __float_as_int(p.w);
  }
  float stop[4]; int topv[4];
#pragma unroll
  for (int k = 0; k < 4; ++k) {
    float ms = cs[0]; int mv = cv[0];
    if (cs[1] > ms || (cs[1] == ms && cv[1] < mv)) { ms = cs[1]; mv = cv[1]; }
#pragma unroll
    for (int off = 1; off < 32; off <<= 1) {
      const float os = __shfl_xor(ms, off); const int ov = __shfl_xor(mv, off);
      if (os > ms || (os == ms && ov < mv)) { ms = os; mv = ov; }
    }
    stop[k] = ms; topv[k] = mv;
    if (cv[0] == mv) cs[0] = -INFINITY;   // v's are globally unique
    if (cv[1] == mv) cs[1] = -INFINITY;
  }

  int bestv = topv[0];
  const int v = topv[j32 & 3];
  if (stop[0] - stop[1] < 1.0f) {   // group-uniform gate (~6% of rows)
    float score = -INFINITY;
    if (j32 < 4) {
      const float* __restrict__ rr2 = rsrc + rb;
      const float* __restrict__ cc2 = cb + (size_t)v * DIM;
      float a1 = 0.0f, a2 = 0.0f;
#pragma unroll 16
      for (int k = 0; k < 384; ++k)
        a1 = __builtin_fmaf(rr2[k], cc2[k], a1);       // kc-block 0, serial
#pragma unroll 16
      for (int k = 384; k < 768; ++k)
        a2 = __builtin_fmaf(rr2[k], cc2[k], a2);       // kc-block 1, serial
      const float dotv = __fadd_rn(a1, a2);            // C += second block
      score = __fsub_rn(__fmul_rn(2.0f, dotv), nrm_np[v]);
    }
    const int gbase = (t & 63) & 32;   // group's first lane within the wave
    float bs = -INFINITY; bestv = 0x7fffffff;
#pragma unroll
    for (int c2 = 0; c2 < 4; ++c2) {
      const float s2 = __shfl(score, gbase + c2);
      const int   v2 = __shfl(v,     gbase + c2);
      if (s2 > bs || (s2 == bs && v2 < bestv)) { bs = s2; bestv = v2; }
    }
  }

  // Phase C: index write + f32 residual/quant chain (bit-identical to np)
  if (j32 == 0) idx_out[(size_t)row * NQ + q] = (float)bestv;
  const float* __restrict__ cbest = cb + (size_t)bestv * DIM;
#pragma unroll
  for (int k = 0; k < 24; ++k) {
    const int e = k * 32 + j32;
    const float cw = cbest[e];
    const float rn = rsrc[rb + e] - cw;
    resid[rb + e] = rn;
    r_hi[rb + e]  = (_Float16)rn;
    quant[rb + e] = (q == 0) ? cw : (quant[rb + e] + cw);
  }
}

// --- out = x + (quant - x), replicating reference elementwise ops -----------
__global__ __launch_bounds__(256) void finalize(const float* __restrict__ x,
                                                float* __restrict__ out) {
  const int stride = gridDim.x * blockDim.x;
  for (int i = blockIdx.x * blockDim.x + threadIdx.x; i < N_ROWS * DIM / 4;
       i += stride) {
    const float4 xv = ((const float4*)x)[i];
    float4 qv = ((float4*)out)[i];
    qv.x = xv.x + (qv.x - xv.x);
    qv.y = xv.y + (qv.y - xv.y);
    qv.z = xv.z + (qv.z - xv.z);
    qv.w = xv.w + (qv.w - xv.w);
    ((float4*)out)[i] = qv;
  }
}

extern "C" void kernel_launch(void* const* d_in, const int* in_sizes, int n_in,
                              void* d_out, int out_size, void* d_ws,
                              size_t ws_size, hipStream_t stream) {
  (void)in_sizes; (void)n_in; (void)out_size; (void)ws_size;
  const float* x  = (const float*)d_in[0];
  const float* cb = (const float*)d_in[1];
  float* out     = (float*)d_out;
  float* quant   = out;
  float* idx_out = out + (size_t)N_ROWS * DIM;

  char* ws = (char*)d_ws;
  auto alloc = [&](size_t bytes) {
    char* p = ws; ws += (bytes + 255) & ~(size_t)255; return p;
  };
  _Float16* cb_hi   = (_Float16*)alloc((size_t)NQ * VCB * DIM * 2);  // 25.2 MB
  _Float16* r_hi    = (_Float16*)alloc((size_t)N_ROWS * DIM * 2);    // 50.3 MB
  float*    resid   = (float*)alloc((size_t)N_ROWS * DIM * 4);       // 100.7 MB
  float*    cb_norm = (float*)alloc((size_t)NQ * VCB * 4);           // 64 KB
  float4*   part    = (float4*)alloc((size_t)N_ROWS * NVB * 16);     // 16.8 MB

  prep_cb<<<NQ * VCB / 4, 256, 0, stream>>>(cb, cb_hi, cb_norm);
  split_x<<<2048, 256, 0, stream>>>(x, r_hi);
  for (int q = 0; q < NQ; ++q) {
    score_topk<<<(N_ROWS / BM) * NVB, 256, 0, stream>>>(
        r_hi, cb_hi + (size_t)q * VCB * DIM, cb_norm + q * VCB, part);
    reduce_update<<<N_ROWS / 8, 256, 0, stream>>>(
        part, cb + (size_t)q * VCB * DIM, cb_norm + q * VCB,
        (q == 0) ? x : resid, resid, quant, idx_out, r_hi, q);
  }
  finalize<<<2048, 256, 0, stream>>>(x, out);
}